// Round 15
// baseline (97.063 us; speedup 1.0000x reference)
//
#include <hip/hip_runtime.h>
#include <hip/hip_bf16.h>

// RNN-T loss forward: B=8, T=128, U=100, V=1024, BLANK=0.
// out = mean_b of -( alpha[tl-2, ul] + blank_lp[tl-2, ul] )
//
// lse_kernel (HBM-floor bound, 424 MB): log-softmax over V; stage the two
//   needed PROBABILITIES as bf16 into diagonal-major staging. Also zeroes the
//   dp done-counter (stream-ordered before dp).
// dp_kernel: one block (9 waves) per batch. Waves 1..8 bulk-copy staging
//   region (29 diagonals) global->LDS + zero pads, release LDS flag; wave 0
//   runs 232 diagonals as PACKED bf16 FMA steps (~6 instr/diag):
//     Pu(packed P0,P1) -> shP=DPP, M=alignbit(Pu,shP,16)=(shP1,P0),
//     Pn = pk_fma(B2, P2, pk_mul(E2, M2)),
//   with wave-max rescale every 8 diagonals (S += log(max)).
//   Fused mean: last finishing block writes out[0] (8 device atomics).

constexpr int Bb = 8;
constexpr int Tt = 128;
constexpr int Uu = 100;
constexpr int Vv = 1024;
constexpr int UP1 = Uu + 1;
constexpr int DROWS = 244;       // global staging rows per batch
constexpr int DPAD  = 104;       // staging row pitch (bf16 elems)
constexpr int LROWS = 233;       // LDS rows d = 0..232
constexpr int REG   = 29;        // diagonals per copy region
constexpr int NREG  = 8;         // 8 * 29 = 232 diagonals

// ---- bf16 helpers --------------------------------------------------------
__device__ __forceinline__ unsigned short f2bf(float f) {
    unsigned int u = __builtin_bit_cast(unsigned int, f);
    u += 0x7fffu + ((u >> 16) & 1u);
    return (unsigned short)(u >> 16);
}
__device__ __forceinline__ float bflo(unsigned int p) {   // low bf16 -> f32
    return __builtin_bit_cast(float, p << 16);
}
__device__ __forceinline__ float bfhi(unsigned int p) {   // high bf16 -> f32
    return __builtin_bit_cast(float, p & 0xffff0000u);
}
// memcpy-based punning (HIP bf16 class types are not trivially copyable)
__device__ __forceinline__ __hip_bfloat162 u2bf(unsigned int p) {
    __hip_bfloat162 h;
    __builtin_memcpy(&h, &p, sizeof(h));
    return h;
}
__device__ __forceinline__ unsigned int bf2u(__hip_bfloat162 h) {
    unsigned int p;
    __builtin_memcpy(&p, &h, sizeof(p));
    return p;
}

// lane l receives lane l-1's value; lane 0 -> 0 (prob identity)
__device__ __forceinline__ unsigned int shr1u(unsigned int x) {
    return (unsigned int)__builtin_amdgcn_update_dpp(
        0, (int)x, 0x138, 0xf, 0xf, true);
}

__device__ __forceinline__ float readlane_f(float x, int lane) {
    return __builtin_bit_cast(float,
        __builtin_amdgcn_readlane(__builtin_bit_cast(int, x), lane));
}
__device__ __forceinline__ unsigned int readlane_u(unsigned int x, int lane) {
    return (unsigned int)__builtin_amdgcn_readlane((int)x, lane);
}

// inclusive max-scan over 64 lanes via DPP (lane 63 = global max)
#define DPP_MAXSTEP(x, ctrl, rmask) {                                        \
    float _t = __builtin_bit_cast(float, __builtin_amdgcn_update_dpp(        \
        __builtin_bit_cast(int, x), __builtin_bit_cast(int, x),              \
        ctrl, rmask, 0xf, false));                                           \
    x = fmaxf(x, _t); }
#define WAVE_SCAN_MAX(x)           \
    DPP_MAXSTEP(x, 0x111, 0xf);    \
    DPP_MAXSTEP(x, 0x112, 0xf);    \
    DPP_MAXSTEP(x, 0x114, 0xf);    \
    DPP_MAXSTEP(x, 0x118, 0xf);    \
    DPP_MAXSTEP(x, 0x142, 0xa);    \
    DPP_MAXSTEP(x, 0x143, 0xc)

// Kernel 1: per (b,t,u) row of V=1024 logits compute lse; stage bf16 PROBS:
//   bS[b][d][u]   = exp(blank_lp[t][u]) at d = t+u+1
//   eS[b][d][u+1] = exp(emit_lp [t][u]) at d = t+u+1
__global__ __launch_bounds__(256) void lse_kernel(
        const float* __restrict__ logits,
        const int*   __restrict__ targets,
        unsigned short* __restrict__ bS,
        unsigned short* __restrict__ eS,
        int* __restrict__ dcnt) {
    if (blockIdx.x == 0 && threadIdx.x == 0)
        __hip_atomic_store(dcnt, 0, __ATOMIC_RELAXED, __HIP_MEMORY_SCOPE_AGENT);

    const int wid  = blockIdx.x * 4 + (threadIdx.x >> 6);   // row index
    const int lane = threadIdx.x & 63;
    const int b   = wid / (Tt * UP1);
    const int rem = wid - b * (Tt * UP1);
    const int t   = rem / UP1;
    const int u   = rem - t * UP1;

    const float* row = logits + (size_t)wid * Vv;
    const float4* r4 = (const float4*)row;
    float4 x0 = r4[lane];
    float4 x1 = r4[lane + 64];
    float4 x2 = r4[lane + 128];
    float4 x3 = r4[lane + 192];

    float m = fmaxf(fmaxf(fmaxf(x0.x, x0.y), fmaxf(x0.z, x0.w)),
                    fmaxf(fmaxf(x1.x, x1.y), fmaxf(x1.z, x1.w)));
    m = fmaxf(m, fmaxf(fmaxf(fmaxf(x2.x, x2.y), fmaxf(x2.z, x2.w)),
                       fmaxf(fmaxf(x3.x, x3.y), fmaxf(x3.z, x3.w))));
    #pragma unroll
    for (int d = 32; d > 0; d >>= 1) m = fmaxf(m, __shfl_xor(m, d, 64));

    float s = __expf(x0.x - m) + __expf(x0.y - m) + __expf(x0.z - m) + __expf(x0.w - m)
            + __expf(x1.x - m) + __expf(x1.y - m) + __expf(x1.z - m) + __expf(x1.w - m)
            + __expf(x2.x - m) + __expf(x2.y - m) + __expf(x2.z - m) + __expf(x2.w - m)
            + __expf(x3.x - m) + __expf(x3.y - m) + __expf(x3.z - m) + __expf(x3.w - m);
    #pragma unroll
    for (int d = 32; d > 0; d >>= 1) s += __shfl_xor(s, d, 64);

    float lse = m + __logf(s);

    if (lane == 0) {
        const int dw = t + u + 1;                       // 1..228
        bS[((size_t)b * DROWS + dw) * DPAD + u] = f2bf(__expf(x0.x - lse));
        if (u < Uu) {
            int tgt = targets[b * Uu + u];
            eS[((size_t)b * DROWS + dw) * DPAD + (u + 1)] = f2bf(__expf(row[tgt] - lse));
        }
    }
}

// Kernel 2: one 576-thread block (9 waves) per batch element; fused mean.
__global__ __launch_bounds__(576) void dp_kernel(
        const unsigned short* __restrict__ bS,
        const unsigned short* __restrict__ eS,
        const int* __restrict__ logit_lengths,
        const int* __restrict__ target_lengths,
        float* __restrict__ nll,
        int*   __restrict__ dcnt,
        float* __restrict__ out) {
    const int b    = blockIdx.x;
    const int tid  = threadIdx.x;
    const int wvi  = tid >> 6;          // 0 = consumer, 1..8 = copy waves
    const int lane = tid & 63;

    __shared__ __align__(16) unsigned short lB[LROWS][DPAD];
    __shared__ __align__(16) unsigned short lE[LROWS][DPAD];
    __shared__ int sflag[NREG];

    if (tid < NREG) sflag[tid] = 0;
    __syncthreads();

    const size_t bstride = (size_t)DROWS * DPAD;

    if (wvi >= 1) {
        // -------- copy wave: region w = rows [1+29w .. 29+29w], both arrays
        const int w = wvi - 1;
        const int row0 = 1 + REG * w;
        constexpr int RBYTES = REG * DPAD * 2;          // 6032 bytes
        const char* gb = (const char*)(bS + (size_t)b * bstride + (size_t)row0 * DPAD);
        const char* ge = (const char*)(eS + (size_t)b * bstride + (size_t)row0 * DPAD);
        char* db = (char*)&lB[row0][0];
        char* de = (char*)&lE[row0][0];
        for (int k = lane * 16; k < RBYTES; k += 64 * 16) {
            *(uint4*)(db + k) = *(const uint4*)(gb + k);
            *(uint4*)(de + k) = *(const uint4*)(ge + k);
        }
        // zero the never-staged pad slots (cols 101..103, eS col 0)
        if (lane < REG) {
            const int d = row0 + lane;
            lB[d][101] = 0; lB[d][102] = 0; lB[d][103] = 0;
            lE[d][0] = 0; lE[d][101] = 0; lE[d][102] = 0; lE[d][103] = 0;
        }
        __hip_atomic_store(&sflag[w], 1, __ATOMIC_RELEASE,
                           __HIP_MEMORY_SCOPE_WORKGROUP);
        return;
    }

    // -------- consumer wave: 232 packed-bf16 FMA steps --------------------
    const int tl = logit_lengths[b];
    const int ul = target_lengths[b];
    const int t_idx = tl - 2;           // reference reads alpha[tl-2][ul]
    const int dcap  = t_idx + ul;       // diagonal of the readout cell

    const int u0 = lane * 2;

    unsigned int Pu = (lane == 0) ? 0x00003F80u : 0u;  // (P0,P1)=(1,0) bf16
    float S  = 0.0f;
    unsigned int capPu = (dcap == 0) ? 0x00003F80u : 0u;
    float capS = 0.0f;

    // packed step: n0 = B.lo*P0 + E.lo*shP1 ; n1 = B.hi*P1 + E.hi*P0
#define PSTEP(dv, ubv, uev) do {                                       \
        unsigned int shP = shr1u(Pu);                                  \
        unsigned int M = __builtin_amdgcn_alignbit(Pu, shP, 16);       \
        Pu = bf2u(__hfma2(u2bf(ubv), u2bf(Pu),                         \
                          __hmul2(u2bf(uev), u2bf(M))));               \
        if ((dv) == dcap) { capPu = Pu; capS = S; }                    \
    } while (0)

#define RESCALE do {                                                   \
        float p0 = bflo(Pu), p1 = bfhi(Pu);                            \
        float gm = fmaxf(p0, p1);                                      \
        WAVE_SCAN_MAX(gm);                                             \
        float mm = fmaxf(readlane_f(gm, 63), 1e-30f);                  \
        float rr = 1.0f / mm;                                          \
        unsigned short rh = f2bf(rr);                                  \
        unsigned int rp = ((unsigned int)rh << 16) | rh;               \
        Pu = bf2u(__hmul2(u2bf(Pu), u2bf(rp)));                        \
        S += __logf(mm);                                               \
    } while (0)

    // group k covers diagonals 8k+1 .. 8k+8 (k = 0..28)
#define LOADG(UB, UE, k) do {                                          \
        _Pragma("unroll")                                              \
        for (int r = 0; r < 8; ++r) {                                  \
            UB[r] = *(const unsigned int*)&lB[(k) * 8 + 1 + r][u0];    \
            UE[r] = *(const unsigned int*)&lE[(k) * 8 + 1 + r][u0];    \
        }                                                              \
    } while (0)

#define COMPG(UB, UE, k) do {                                          \
        _Pragma("unroll")                                              \
        for (int r = 0; r < 8; ++r)                                    \
            PSTEP((k) * 8 + 1 + r, UB[r], UE[r]);                      \
        RESCALE;                                                       \
    } while (0)

    int wcur = -1;
#define ENSURE(wn) do {                                                \
        while (wcur < (wn)) {                                          \
            ++wcur;                                                    \
            while (__hip_atomic_load(&sflag[wcur], __ATOMIC_ACQUIRE,   \
                       __HIP_MEMORY_SCOPE_WORKGROUP) == 0)             \
                __builtin_amdgcn_s_sleep(1);                           \
        }                                                              \
    } while (0)

    unsigned int Ab[8], Ae[8], Bb_[8], Be_[8];
    ENSURE(7 / REG);                    // region of group 0
    LOADG(Ab, Ae, 0);
    for (int c = 0; c < 14; ++c) {
        const int k0 = 2 * c, k1 = 2 * c + 1;
        ENSURE((8 * k1 + 7) / REG);
        LOADG(Bb_, Be_, k1);
        COMPG(Ab, Ae, k0);
        if (k1 < 28) {
            ENSURE((8 * (k1 + 1) + 7) / REG);
            LOADG(Ab, Ae, k1 + 1);
        }
        COMPG(Bb_, Be_, k1);
    }
    COMPG(Ab, Ae, 28);                  // group 28 -> diagonal 232
#undef PSTEP
#undef RESCALE
#undef LOADG
#undef COMPG
#undef ENSURE

    // readout: packed cap value lives on lane ul>>1
    unsigned int cw = readlane_u(capPu, ul >> 1);
    float capv = (ul & 1) ? bfhi(cw) : bflo(cw);

    if (lane == 0) {
        float blk = __builtin_bit_cast(float, ((unsigned int)lB[dcap + 1][ul]) << 16);
        float ll = __logf(capv) + capS + __logf(blk);
        __hip_atomic_store(&nll[b], -ll, __ATOMIC_RELEASE,
                           __HIP_MEMORY_SCOPE_AGENT);
        int prev = __hip_atomic_fetch_add(dcnt, 1, __ATOMIC_ACQ_REL,
                                          __HIP_MEMORY_SCOPE_AGENT);
        if (prev == Bb - 1) {           // last dp block: write the mean
            float s = 0.0f;
            for (int i = 0; i < Bb; ++i)
                s += __hip_atomic_load(&nll[i], __ATOMIC_ACQUIRE,
                                       __HIP_MEMORY_SCOPE_AGENT);
            out[0] = s / (float)Bb;
        }
    }
}

extern "C" void kernel_launch(void* const* d_in, const int* in_sizes, int n_in,
                              void* d_out, int out_size, void* d_ws, size_t ws_size,
                              hipStream_t stream) {
    const float* logits         = (const float*)d_in[0];
    const int*   targets        = (const int*)d_in[1];
    const int*   logit_lengths  = (const int*)d_in[2];
    const int*   target_lengths = (const int*)d_in[3];
    float* out = (float*)d_out;

    int* dcnt = (int*)d_ws;                              // 1 int (+pad to 16B)
    unsigned short* bS = (unsigned short*)d_ws + 8;      // 8*244*104 bf16
    unsigned short* eS = bS + (size_t)Bb * DROWS * DPAD;
    float* nll = (float*)(eS + (size_t)Bb * DROWS * DPAD);   // 8 floats

    const int rows = Bb * Tt * UP1;                      // 103424, divisible by 4
    lse_kernel<<<rows / 4, 256, 0, stream>>>(logits, targets, bS, eS, dcnt);
    dp_kernel<<<Bb, 576, 0, stream>>>(bS, eS, logit_lengths, target_lengths,
                                      nll, dcnt, out);
}

// Round 16
// 88.807 us; speedup vs baseline: 1.0930x; 1.0930x over previous
//
#include <hip/hip_runtime.h>

// RNN-T loss forward: B=8, T=128, U=100, V=1024, BLANK=0.
// out = mean_b of -( alpha[tl-2, ul] + blank_lp[tl-2, ul] )
//
// lse_kernel (HBM-floor, 424 MB): log-softmax over V; stage the two needed
//   PROBABILITIES (bf16) into diagonal-major interleaved staging
//   gS[b][d][u>>1][B0,B1,E0,E1]. Zeroes dp's done-counter.
// dp_kernel: one block (9 waves) per batch. Waves 1..8: issue-all 12 uint4
//   loads of region w (29 diagonal rows) then bulk-write LDS + zero pads,
//   release LDS flag. Wave 0: 232 diagonals of f32 FMA
//     n1 = fma(P1,B1, P0*E1); n0 = fma(P0,B0, shr1(P1)*E0)
//   (one ds_read_b64 per diagonal), wave-max rescale every 8 diagonals.
//   Fused mean via 8 device-scope atomics (r15-proven tail).

constexpr int Bb = 8;
constexpr int Tt = 128;
constexpr int Uu = 100;
constexpr int Vv = 1024;
constexpr int UP1 = Uu + 1;
constexpr int DROWS = 244;        // global staging rows per batch
constexpr int PAIRS = 52;         // u-pairs per row
constexpr int ROWB  = PAIRS * 8;  // 416 bytes per row
constexpr int LROWS = 233;        // LDS rows d = 0..232
constexpr int REG   = 29;         // diagonals per copy region
constexpr int NREG  = 8;          // 8 * 29 = 232 diagonals
constexpr int RBYTES = REG * ROWB;  // 12064 bytes per region

// ---- bf16 helpers --------------------------------------------------------
__device__ __forceinline__ unsigned short f2bf(float f) {
    unsigned int u = __builtin_bit_cast(unsigned int, f);
    u += 0x7fffu + ((u >> 16) & 1u);
    return (unsigned short)(u >> 16);
}
__device__ __forceinline__ float bflo(unsigned int p) {   // low bf16 -> f32
    return __builtin_bit_cast(float, p << 16);
}
__device__ __forceinline__ float bfhi(unsigned int p) {   // high bf16 -> f32
    return __builtin_bit_cast(float, p & 0xffff0000u);
}

// lane l receives lane l-1's value; lane 0 -> 0 (prob identity)
__device__ __forceinline__ float wave_shr1(float x) {
    return __builtin_bit_cast(float, __builtin_amdgcn_update_dpp(
        0, __builtin_bit_cast(int, x), 0x138, 0xf, 0xf, true));
}
__device__ __forceinline__ float readlane_f(float x, int lane) {
    return __builtin_bit_cast(float,
        __builtin_amdgcn_readlane(__builtin_bit_cast(int, x), lane));
}

// inclusive max-scan over 64 lanes via DPP (lane 63 = global max)
#define DPP_MAXSTEP(x, ctrl, rmask) {                                        \
    float _t = __builtin_bit_cast(float, __builtin_amdgcn_update_dpp(        \
        __builtin_bit_cast(int, x), __builtin_bit_cast(int, x),              \
        ctrl, rmask, 0xf, false));                                           \
    x = fmaxf(x, _t); }
#define WAVE_SCAN_MAX(x)           \
    DPP_MAXSTEP(x, 0x111, 0xf);    \
    DPP_MAXSTEP(x, 0x112, 0xf);    \
    DPP_MAXSTEP(x, 0x114, 0xf);    \
    DPP_MAXSTEP(x, 0x118, 0xf);    \
    DPP_MAXSTEP(x, 0x142, 0xa);    \
    DPP_MAXSTEP(x, 0x143, 0xc)

// Kernel 1: per (b,t,u) row of V=1024 logits compute lse; stage bf16 PROBS
// interleaved: row d = t+u+1; blank -> [d][u>>1][u&1]; emit -> with s=u+1,
// [d][s>>1][2+(s&1)].
__global__ __launch_bounds__(256) void lse_kernel(
        const float* __restrict__ logits,
        const int*   __restrict__ targets,
        unsigned short* __restrict__ gS,
        int* __restrict__ dcnt) {
    if (blockIdx.x == 0 && threadIdx.x == 0)
        __hip_atomic_store(dcnt, 0, __ATOMIC_RELAXED, __HIP_MEMORY_SCOPE_AGENT);

    const int wid  = blockIdx.x * 4 + (threadIdx.x >> 6);   // row index
    const int lane = threadIdx.x & 63;
    const int b   = wid / (Tt * UP1);
    const int rem = wid - b * (Tt * UP1);
    const int t   = rem / UP1;
    const int u   = rem - t * UP1;

    const float* row = logits + (size_t)wid * Vv;
    const float4* r4 = (const float4*)row;
    float4 x0 = r4[lane];
    float4 x1 = r4[lane + 64];
    float4 x2 = r4[lane + 128];
    float4 x3 = r4[lane + 192];

    float m = fmaxf(fmaxf(fmaxf(x0.x, x0.y), fmaxf(x0.z, x0.w)),
                    fmaxf(fmaxf(x1.x, x1.y), fmaxf(x1.z, x1.w)));
    m = fmaxf(m, fmaxf(fmaxf(fmaxf(x2.x, x2.y), fmaxf(x2.z, x2.w)),
                       fmaxf(fmaxf(x3.x, x3.y), fmaxf(x3.z, x3.w))));
    #pragma unroll
    for (int d = 32; d > 0; d >>= 1) m = fmaxf(m, __shfl_xor(m, d, 64));

    float s = __expf(x0.x - m) + __expf(x0.y - m) + __expf(x0.z - m) + __expf(x0.w - m)
            + __expf(x1.x - m) + __expf(x1.y - m) + __expf(x1.z - m) + __expf(x1.w - m)
            + __expf(x2.x - m) + __expf(x2.y - m) + __expf(x2.z - m) + __expf(x2.w - m)
            + __expf(x3.x - m) + __expf(x3.y - m) + __expf(x3.z - m) + __expf(x3.w - m);
    #pragma unroll
    for (int d = 32; d > 0; d >>= 1) s += __shfl_xor(s, d, 64);

    float lse = m + __logf(s);

    if (lane == 0) {
        const int dw = t + u + 1;                       // 1..228
        const size_t rowoff = ((size_t)b * DROWS + dw) * (PAIRS * 4);
        gS[rowoff + (u >> 1) * 4 + (u & 1)] = f2bf(__expf(x0.x - lse));
        if (u < Uu) {
            int tgt = targets[b * Uu + u];
            const int sidx = u + 1;
            gS[rowoff + (sidx >> 1) * 4 + 2 + (sidx & 1)] = f2bf(__expf(row[tgt] - lse));
        }
    }
}

// Kernel 2: one 576-thread block (9 waves) per batch element; fused mean.
__global__ __launch_bounds__(576) void dp_kernel(
        const unsigned short* __restrict__ gS,
        const int* __restrict__ logit_lengths,
        const int* __restrict__ target_lengths,
        float* __restrict__ nll,
        int*   __restrict__ dcnt,
        float* __restrict__ out) {
    const int b    = blockIdx.x;
    const int tid  = threadIdx.x;
    const int wvi  = tid >> 6;          // 0 = consumer, 1..8 = copy waves
    const int lane = tid & 63;

    __shared__ __align__(16) unsigned short lBE[LROWS][PAIRS][4];
    __shared__ int sflag[NREG];

    if (tid < NREG) sflag[tid] = 0;
    __syncthreads();

    if (wvi >= 1) {
        // ---- copy wave: region w = rows [1+29w .. 29+29w] -----------------
        const int w = wvi - 1;
        const int row0 = 1 + REG * w;
        const char* gb = (const char*)gS + ((size_t)b * DROWS + row0) * ROWB;
        char* db = (char*)lBE + (size_t)row0 * ROWB;

        uint4 v[12];
        #pragma unroll
        for (int i = 0; i < 12; ++i)
            v[i] = *(const uint4*)(gb + lane * 16 + i * 1024);
        #pragma unroll
        for (int i = 0; i < 11; ++i)
            *(uint4*)(db + lane * 16 + i * 1024) = v[i];
        if (lane < 50)                               // 50*16+11264 < 12064
            *(uint4*)(db + lane * 16 + 11 * 1024) = v[11];

        // zero never-staged pads: E slot s=0; u=101 B/E; pair 51 entirely
        if (lane < REG) {
            const int d = row0 + lane;
            lBE[d][0][2]  = 0;
            lBE[d][50][1] = 0;
            lBE[d][50][3] = 0;
            lBE[d][51][0] = 0; lBE[d][51][1] = 0;
            lBE[d][51][2] = 0; lBE[d][51][3] = 0;
        }
        __hip_atomic_store(&sflag[w], 1, __ATOMIC_RELEASE,
                           __HIP_MEMORY_SCOPE_WORKGROUP);
        return;
    }

    // ---- consumer wave: 232 f32-FMA steps --------------------------------
    const int tl = logit_lengths[b];
    const int ul = target_lengths[b];
    const int t_idx = tl - 2;           // reference reads alpha[tl-2][ul]
    const int dcap  = t_idx + ul;       // diagonal of the readout cell

    const int lpair = (lane < 51) ? lane : 51;   // clamp: lanes>=51 read zeros
    const char* lbase = (const char*)lBE + lpair * 8;

    float P0 = (lane == 0) ? 1.0f : 0.0f;   // exp(alpha) on diag 0
    float P1 = 0.0f;
    float S  = 0.0f;
    float capP0 = (dcap == 0) ? 1.0f : 0.0f, capP1 = 0.0f, capS = 0.0f;

#define PSTEP(dv, w0, w1) do {                                         \
        float Bx = bflo(w0), By = bfhi(w0);                            \
        float Ex = bflo(w1), Ey = bfhi(w1);                            \
        float sh = wave_shr1(P1);                                      \
        float n1 = fmaf(P1, By, P0 * Ey);                              \
        float n0 = fmaf(P0, Bx, sh * Ex);                              \
        P0 = n0; P1 = n1;                                              \
        if ((dv) == dcap) { capP0 = n0; capP1 = n1; capS = S; }        \
    } while (0)

#define RESCALE do {                                                   \
        float gm = fmaxf(P0, P1);                                      \
        WAVE_SCAN_MAX(gm);                                             \
        float mm = fmaxf(readlane_f(gm, 63), 1e-30f);                  \
        float rr = 1.0f / mm;                                          \
        P0 *= rr; P1 *= rr;                                            \
        S += __logf(mm);                                               \
    } while (0)

    // group k covers diagonals 8k+1 .. 8k+8 (k = 0..28)
#define LOADG(UB, UE, k) do {                                          \
        _Pragma("unroll")                                              \
        for (int r = 0; r < 8; ++r) {                                  \
            uint2 q = *(const uint2*)(lbase +                          \
                        (size_t)((k) * 8 + 1 + r) * ROWB);             \
            UB[r] = q.x; UE[r] = q.y;                                  \
        }                                                              \
    } while (0)

#define COMPG(UB, UE, k) do {                                          \
        _Pragma("unroll")                                              \
        for (int r = 0; r < 8; ++r)                                    \
            PSTEP((k) * 8 + 1 + r, UB[r], UE[r]);                      \
        RESCALE;                                                       \
    } while (0)

    int wcur = -1;
#define ENSURE(wn) do {                                                \
        while (wcur < (wn)) {                                          \
            ++wcur;                                                    \
            while (__hip_atomic_load(&sflag[wcur], __ATOMIC_ACQUIRE,   \
                       __HIP_MEMORY_SCOPE_WORKGROUP) == 0)             \
                __builtin_amdgcn_s_sleep(1);                           \
        }                                                              \
    } while (0)

    unsigned int Ab[8], Ae[8], Bb_[8], Be_[8];
    ENSURE(0);
    LOADG(Ab, Ae, 0);
    for (int c = 0; c < 14; ++c) {
        const int k0 = 2 * c, k1 = 2 * c + 1;
        ENSURE((8 * k1 + 7) / REG);
        LOADG(Bb_, Be_, k1);
        COMPG(Ab, Ae, k0);
        if (k1 < 28) {
            ENSURE((8 * (k1 + 1) + 7) / REG);
            LOADG(Ab, Ae, k1 + 1);
        }
        COMPG(Bb_, Be_, k1);
    }
    COMPG(Ab, Ae, 28);                  // group 28 -> diagonal 232
#undef PSTEP
#undef RESCALE
#undef LOADG
#undef COMPG
#undef ENSURE

    // readout: cap value lives on lane ul>>1, slot ul&1
    float w0 = readlane_f(capP0, ul >> 1);
    float w1 = readlane_f(capP1, ul >> 1);
    float capv = (ul & 1) ? w1 : w0;

    if (lane == 0) {
        unsigned short hv = lBE[dcap + 1][ul >> 1][ul & 1];  // blank prob
        float blk = __builtin_bit_cast(float, ((unsigned int)hv) << 16);
        float ll = __logf(capv) + capS + __logf(blk);
        __hip_atomic_store(&nll[b], -ll, __ATOMIC_RELEASE,
                           __HIP_MEMORY_SCOPE_AGENT);
        int prev = __hip_atomic_fetch_add(dcnt, 1, __ATOMIC_ACQ_REL,
                                          __HIP_MEMORY_SCOPE_AGENT);
        if (prev == Bb - 1) {           // last dp block: write the mean
            float s = 0.0f;
            for (int i = 0; i < Bb; ++i)
                s += __hip_atomic_load(&nll[i], __ATOMIC_ACQUIRE,
                                       __HIP_MEMORY_SCOPE_AGENT);
            out[0] = s / (float)Bb;
        }
    }
}

extern "C" void kernel_launch(void* const* d_in, const int* in_sizes, int n_in,
                              void* d_out, int out_size, void* d_ws, size_t ws_size,
                              hipStream_t stream) {
    const float* logits         = (const float*)d_in[0];
    const int*   targets        = (const int*)d_in[1];
    const int*   logit_lengths  = (const int*)d_in[2];
    const int*   target_lengths = (const int*)d_in[3];
    float* out = (float*)d_out;

    int* dcnt = (int*)d_ws;                              // 1 int (16B pad)
    unsigned short* gS = (unsigned short*)d_ws + 16;     // 8*244*52*4 bf16
    float* nll = (float*)(gS + (size_t)Bb * DROWS * PAIRS * 4);  // 8 floats

    const int rows = Bb * Tt * UP1;                      // 103424, divisible by 4
    lse_kernel<<<rows / 4, 256, 0, stream>>>(logits, targets, gS, dcnt);
    dp_kernel<<<Bb, 576, 0, stream>>>(gS, logit_lengths, target_lengths,
                                      nll, dcnt, out);
}